// Round 1
// baseline (489.919 us; speedup 1.0000x reference)
//
#include <hip/hip_runtime.h>

// ---------------------------------------------------------------------------
// Transducer joint network:
//   he = enc @ W1e^T   (1024 x 512, K=512)
//   hd = dec @ W1d^T   ( 256 x 512, K=512)
//   h  = tanh(he[bt,:] + hd[bu,:] + b1)      (never materialized)
//   out[r, v] = sum_k h[r,k] * W2[v,k] + b2[v]   (65536 x 1000, K=512)
// Strategy: bf16 MFMA (16x16x32) for both GEMM stages; tanh fused into the
// A-tile LDS staging of the big GEMM.
// ---------------------------------------------------------------------------

typedef __bf16 bf16x8 __attribute__((ext_vector_type(8)));
typedef float  f32x4  __attribute__((ext_vector_type(4)));

#define B_   4
#define T_   256
#define U_   64
#define D_   512
#define K_   512
#define V_   1000

__device__ __forceinline__ float tanh_fast(float x) {
    // tanh(x) = 1 - 2/(exp(2x)+1); stable at both infinities.
    float e = __expf(2.0f * x);
    float r = __builtin_amdgcn_rcpf(e + 1.0f);
    return fmaf(-2.0f, r, 1.0f);
}

// ---------------- W2 fp32 -> bf16 convert (1000*512 = 512000 elems) --------
__global__ __launch_bounds__(256) void w2conv_kernel(const float* __restrict__ W2,
                                                     __bf16* __restrict__ W2b) {
    int idx = (blockIdx.x * 256 + threadIdx.x) * 8;   // grid sized exactly
    const f32x4* p = (const f32x4*)(W2 + idx);
    f32x4 a = p[0], b = p[1];
    bf16x8 o;
#pragma unroll
    for (int j = 0; j < 4; ++j) { o[j] = (__bf16)a[j]; o[4 + j] = (__bf16)b[j]; }
    *(bf16x8*)(W2b + idx) = o;
}

// ---------------- stage 1: he and hd via bf16 MFMA -------------------------
// virtual rows: 0..1023 -> enc (weights W1[:, :512]) ; 1024..1279 -> dec
// (weights W1[:, 512:]).  64x64 output tile per block, 4 waves of 32x32.
__global__ __launch_bounds__(256) void stage1_kernel(const float* __restrict__ enc,
                                                     const float* __restrict__ dec,
                                                     const float* __restrict__ W1,
                                                     float* __restrict__ he,
                                                     float* __restrict__ hd) {
    const int ct = blockIdx.x;            // k-col tile 0..7
    const int rt = blockIdx.y;            // row tile 0..19
    const bool isDec = rt >= 16;
    const float* X = isDec ? (dec + (rt - 16) * 64 * D_) : (enc + rt * 64 * D_);
    const int   woff = isDec ? D_ : 0;
    float*      Y = isDec ? (hd + (rt - 16) * 64 * K_) : (he + rt * 64 * K_);
    const int   k0 = ct * 64;

    __shared__ __align__(16) __bf16 As[64][72];
    __shared__ __align__(16) __bf16 Bs[64][72];

    const int tid  = threadIdx.x;
    const int lane = tid & 63, w = tid >> 6;
    const int wm = (w >> 1) * 32, wn = (w & 1) * 32;
    const int q = lane >> 4, li = lane & 15;

    f32x4 acc[2][2] = {};

    for (int d0 = 0; d0 < D_; d0 += 64) {
        __syncthreads();
#pragma unroll
        for (int i = 0; i < 2; ++i) {
            int s = tid + i * 256;        // 512 tasks per matrix
            int r = s >> 3, kc = s & 7;
            // A tile (input rows)
            const f32x4* xp = (const f32x4*)(X + r * D_ + d0 + kc * 8);
            f32x4 x0 = xp[0], x1 = xp[1];
            bf16x8 a;
#pragma unroll
            for (int j = 0; j < 4; ++j) { a[j] = (__bf16)x0[j]; a[4 + j] = (__bf16)x1[j]; }
            *(bf16x8*)&As[r][kc * 8] = a;
            // B tile (W1 rows = output k index)
            const f32x4* wp = (const f32x4*)(W1 + (k0 + r) * (2 * D_) + woff + d0 + kc * 8);
            f32x4 w0 = wp[0], w1 = wp[1];
            bf16x8 b;
#pragma unroll
            for (int j = 0; j < 4; ++j) { b[j] = (__bf16)w0[j]; b[4 + j] = (__bf16)w1[j]; }
            *(bf16x8*)&Bs[r][kc * 8] = b;
        }
        __syncthreads();
#pragma unroll
        for (int kk = 0; kk < 64; kk += 32) {
            bf16x8 af[2], bfr[2];
#pragma unroll
            for (int mi = 0; mi < 2; ++mi) af[mi]  = *(const bf16x8*)&As[wm + mi * 16 + li][kk + q * 8];
#pragma unroll
            for (int ni = 0; ni < 2; ++ni) bfr[ni] = *(const bf16x8*)&Bs[wn + ni * 16 + li][kk + q * 8];
#pragma unroll
            for (int mi = 0; mi < 2; ++mi)
#pragma unroll
                for (int ni = 0; ni < 2; ++ni)
                    acc[mi][ni] = __builtin_amdgcn_mfma_f32_16x16x32_bf16(af[mi], bfr[ni], acc[mi][ni], 0, 0, 0);
        }
    }
    // epilogue: C/D layout col=lane&15, row=(lane>>4)*4+reg
#pragma unroll
    for (int mi = 0; mi < 2; ++mi)
#pragma unroll
        for (int ni = 0; ni < 2; ++ni) {
            int row0 = wm + mi * 16 + q * 4;
            int col  = k0 + wn + ni * 16 + li;
            float* yp = Y + row0 * K_ + col;
            yp[0 * K_] = acc[mi][ni][0];
            yp[1 * K_] = acc[mi][ni][1];
            yp[2 * K_] = acc[mi][ni][2];
            yp[3 * K_] = acc[mi][ni][3];
        }
}

// ---------------- stage 2: fused tanh + big GEMM ---------------------------
// 128x128 output tile per block; rows of tile = 2 t-values x 64 u-values.
// 4 waves, each computes 64x64 via 4x4 grid of 16x16x32 bf16 MFMA. BK=64.
__global__ __launch_bounds__(256) void joint_kernel(const float* __restrict__ he,
                                                    const float* __restrict__ hd,
                                                    const float* __restrict__ b1,
                                                    const __bf16* __restrict__ W2b,
                                                    const float* __restrict__ b2,
                                                    float* __restrict__ out) {
    const int ct = blockIdx.x;            // col tile 0..7  (V padded to 1024)
    const int rt = blockIdx.y;            // row tile 0..511
    const int e0  = 2 * rt;               // he rows e0, e0+1
    const int hd0 = (rt >> 7) * 64;       // hd row base = b*64

    __shared__ __align__(16) __bf16 As[128][72];
    __shared__ __align__(16) __bf16 Bs[128][72];

    const int tid  = threadIdx.x;
    const int lane = tid & 63, w = tid >> 6;
    const int wm = (w >> 1) * 64, wn = (w & 1) * 64;
    const int q = lane >> 4, li = lane & 15;

    f32x4 acc[4][4] = {};

    for (int k0 = 0; k0 < K_; k0 += 64) {
        __syncthreads();
#pragma unroll
        for (int i = 0; i < 4; ++i) {
            int s = tid + i * 256;        // 1024 tasks: 128 rows x 8 k-chunks
            int m = s >> 3, kc = s & 7;
            int k = k0 + kc * 8;
            // ---- A tile: tanh(he + hd + b1), cast bf16
            const f32x4* hp = (const f32x4*)(he + (e0 + (m >> 6)) * K_ + k);
            const f32x4* dp = (const f32x4*)(hd + (hd0 + (m & 63)) * K_ + k);
            const f32x4* bp = (const f32x4*)(b1 + k);
            f32x4 s0 = hp[0] + dp[0] + bp[0];
            f32x4 s1 = hp[1] + dp[1] + bp[1];
            bf16x8 a;
#pragma unroll
            for (int j = 0; j < 4; ++j) {
                a[j]     = (__bf16)tanh_fast(s0[j]);
                a[4 + j] = (__bf16)tanh_fast(s1[j]);
            }
            *(bf16x8*)&As[m][kc * 8] = a;
            // ---- B tile: W2 rows (already bf16)
            int v = ct * 128 + m;
            bf16x8 wv;
#pragma unroll
            for (int j = 0; j < 8; ++j) wv[j] = (__bf16)0.0f;
            if (v < V_) wv = *(const bf16x8*)(W2b + v * K_ + k);
            *(bf16x8*)&Bs[m][kc * 8] = wv;
        }
        __syncthreads();
#pragma unroll
        for (int kk = 0; kk < 64; kk += 32) {
            bf16x8 af[4], bfr[4];
#pragma unroll
            for (int mi = 0; mi < 4; ++mi) af[mi]  = *(const bf16x8*)&As[wm + mi * 16 + li][kk + q * 8];
#pragma unroll
            for (int ni = 0; ni < 4; ++ni) bfr[ni] = *(const bf16x8*)&Bs[wn + ni * 16 + li][kk + q * 8];
#pragma unroll
            for (int mi = 0; mi < 4; ++mi)
#pragma unroll
                for (int ni = 0; ni < 4; ++ni)
                    acc[mi][ni] = __builtin_amdgcn_mfma_f32_16x16x32_bf16(af[mi], bfr[ni], acc[mi][ni], 0, 0, 0);
        }
    }

    // epilogue: out[r*1000 + v] = acc + b2[v]
    const long rbase = (long)rt * 128 + wm;
#pragma unroll
    for (int ni = 0; ni < 4; ++ni) {
        int gv = ct * 128 + wn + ni * 16 + li;
        if (gv < V_) {
            float bb = b2[gv];
#pragma unroll
            for (int mi = 0; mi < 4; ++mi) {
                long r0 = rbase + mi * 16 + q * 4;
                float* op = out + r0 * V_ + gv;
                op[0 * V_] = acc[mi][ni][0] + bb;
                op[1 * V_] = acc[mi][ni][1] + bb;
                op[2 * V_] = acc[mi][ni][2] + bb;
                op[3 * V_] = acc[mi][ni][3] + bb;
            }
        }
    }
}

extern "C" void kernel_launch(void* const* d_in, const int* in_sizes, int n_in,
                              void* d_out, int out_size, void* d_ws, size_t ws_size,
                              hipStream_t stream) {
    const float* enc = (const float*)d_in[0];   // (4,256,512)
    const float* dec = (const float*)d_in[1];   // (4,64,512)
    const float* W1  = (const float*)d_in[2];   // (512,1024)
    const float* b1  = (const float*)d_in[3];   // (512,)
    const float* W2  = (const float*)d_in[4];   // (1000,512)
    const float* b2  = (const float*)d_in[5];   // (1000,)
    float* out = (float*)d_out;                 // (4,256,64,1000) fp32

    // workspace layout (3.65 MB total)
    float*  he  = (float*)d_ws;                 // 1024*512 fp32
    float*  hd  = he + 1024 * K_;               //  256*512 fp32
    __bf16* W2b = (__bf16*)(hd + 256 * K_);     // 1000*512 bf16

    w2conv_kernel<<<dim3(250), dim3(256), 0, stream>>>(W2, W2b);
    stage1_kernel<<<dim3(8, 20), dim3(256), 0, stream>>>(enc, dec, W1, he, hd);
    joint_kernel<<<dim3(8, 512), dim3(256), 0, stream>>>(he, hd, b1, W2b, b2, out);
}

// Round 2
// 443.599 us; speedup vs baseline: 1.1044x; 1.1044x over previous
//
#include <hip/hip_runtime.h>

// ---------------------------------------------------------------------------
// Transducer joint network, round 2:
//   stage1: he = enc @ W1e^T (1024x512), hd = dec @ W1d^T (256x512)  [bf16 MFMA]
//   hker : h[r,k] = tanh(he[r>>6,k] + hd[(r>>14)*64+(r&63),k] + b1[k]) -> bf16 (ws)
//   joint: out[r,v] = sum_k h[r,k]*W2[v,k] + b2[v]   (65536x1000, K=512)
//          m97-style: global_load_lds(16B) staging, 128x128 tile, BK=64,
//          XOR k-chunk swizzle so frag ds_read_b128 is 2-way (free) conflict.
// ---------------------------------------------------------------------------

typedef __bf16 bf16x8 __attribute__((ext_vector_type(8)));
typedef float  f32x4  __attribute__((ext_vector_type(4)));

#define B_   4
#define T_   256
#define U_   64
#define D_   512
#define K_   512
#define V_   1000
#define ROWS_ 65536L

__device__ __forceinline__ float tanh_fast(float x) {
    float e = __expf(2.0f * x);
    float r = __builtin_amdgcn_rcpf(e + 1.0f);
    return fmaf(-2.0f, r, 1.0f);
}

__device__ __forceinline__ void gl_lds16(const void* g, void* l) {
    __builtin_amdgcn_global_load_lds(
        (const __attribute__((address_space(1))) unsigned int*)g,
        (__attribute__((address_space(3))) unsigned int*)l,
        16, 0, 0);
}

// ---------------- W2 fp32 -> bf16, padded to 1024 rows (zeros) -------------
__global__ __launch_bounds__(256) void w2conv_kernel(const float* __restrict__ W2,
                                                     __bf16* __restrict__ W2b) {
    int idx = (blockIdx.x * 256 + threadIdx.x) * 8;   // over 1024*512 elems
    int v = idx >> 9;
    bf16x8 o;
    if (v < V_) {
        const f32x4* p = (const f32x4*)(W2 + idx);
        f32x4 a = p[0], b = p[1];
#pragma unroll
        for (int j = 0; j < 4; ++j) { o[j] = (__bf16)a[j]; o[4 + j] = (__bf16)b[j]; }
    } else {
#pragma unroll
        for (int j = 0; j < 8; ++j) o[j] = (__bf16)0.0f;
    }
    *(bf16x8*)(W2b + idx) = o;
}

// ---------------- stage 1: he and hd via bf16 MFMA (unchanged, verified) ---
__global__ __launch_bounds__(256) void stage1_kernel(const float* __restrict__ enc,
                                                     const float* __restrict__ dec,
                                                     const float* __restrict__ W1,
                                                     float* __restrict__ he,
                                                     float* __restrict__ hd) {
    const int ct = blockIdx.x;            // k-col tile 0..7
    const int rt = blockIdx.y;            // row tile 0..19
    const bool isDec = rt >= 16;
    const float* X = isDec ? (dec + (rt - 16) * 64 * D_) : (enc + rt * 64 * D_);
    const int   woff = isDec ? D_ : 0;
    float*      Y = isDec ? (hd + (rt - 16) * 64 * K_) : (he + rt * 64 * K_);
    const int   k0 = ct * 64;

    __shared__ __align__(16) __bf16 As[64][72];
    __shared__ __align__(16) __bf16 Bs[64][72];

    const int tid  = threadIdx.x;
    const int lane = tid & 63, w = tid >> 6;
    const int wm = (w >> 1) * 32, wn = (w & 1) * 32;
    const int q = lane >> 4, li = lane & 15;

    f32x4 acc[2][2] = {};

    for (int d0 = 0; d0 < D_; d0 += 64) {
        __syncthreads();
#pragma unroll
        for (int i = 0; i < 2; ++i) {
            int s = tid + i * 256;
            int r = s >> 3, kc = s & 7;
            const f32x4* xp = (const f32x4*)(X + r * D_ + d0 + kc * 8);
            f32x4 x0 = xp[0], x1 = xp[1];
            bf16x8 a;
#pragma unroll
            for (int j = 0; j < 4; ++j) { a[j] = (__bf16)x0[j]; a[4 + j] = (__bf16)x1[j]; }
            *(bf16x8*)&As[r][kc * 8] = a;
            const f32x4* wp = (const f32x4*)(W1 + (k0 + r) * (2 * D_) + woff + d0 + kc * 8);
            f32x4 w0 = wp[0], w1 = wp[1];
            bf16x8 b;
#pragma unroll
            for (int j = 0; j < 4; ++j) { b[j] = (__bf16)w0[j]; b[4 + j] = (__bf16)w1[j]; }
            *(bf16x8*)&Bs[r][kc * 8] = b;
        }
        __syncthreads();
#pragma unroll
        for (int kk = 0; kk < 64; kk += 32) {
            bf16x8 af[2], bfr[2];
#pragma unroll
            for (int mi = 0; mi < 2; ++mi) af[mi]  = *(const bf16x8*)&As[wm + mi * 16 + li][kk + q * 8];
#pragma unroll
            for (int ni = 0; ni < 2; ++ni) bfr[ni] = *(const bf16x8*)&Bs[wn + ni * 16 + li][kk + q * 8];
#pragma unroll
            for (int mi = 0; mi < 2; ++mi)
#pragma unroll
                for (int ni = 0; ni < 2; ++ni)
                    acc[mi][ni] = __builtin_amdgcn_mfma_f32_16x16x32_bf16(af[mi], bfr[ni], acc[mi][ni], 0, 0, 0);
        }
    }
#pragma unroll
    for (int mi = 0; mi < 2; ++mi)
#pragma unroll
        for (int ni = 0; ni < 2; ++ni) {
            int row0 = wm + mi * 16 + q * 4;
            int col  = k0 + wn + ni * 16 + li;
            float* yp = Y + row0 * K_ + col;
            yp[0 * K_] = acc[mi][ni][0];
            yp[1 * K_] = acc[mi][ni][1];
            yp[2 * K_] = acc[mi][ni][2];
            yp[3 * K_] = acc[mi][ni][3];
        }
}

// ---------------- h precompute: tanh(he+hd+b1) -> bf16 ---------------------
// block = 256 threads = 4 rows x 64 k-chunks of 8.
__global__ __launch_bounds__(256) void h_kernel(const float* __restrict__ he,
                                                const float* __restrict__ hd,
                                                const float* __restrict__ b1,
                                                __bf16* __restrict__ h,
                                                long r0) {
    const int tid = threadIdx.x;
    const long rl = (long)blockIdx.x * 4 + (tid >> 6);   // local row in chunk
    const long r  = r0 + rl;                             // global row
    const int  k8 = (tid & 63) * 8;
    const long het = r >> 6;
    const long hdr = (r >> 14) * 64 + (r & 63);
    const f32x4* hp = (const f32x4*)(he + het * K_ + k8);
    const f32x4* dp = (const f32x4*)(hd + hdr * K_ + k8);
    const f32x4* bp = (const f32x4*)(b1 + k8);
    f32x4 s0 = hp[0] + dp[0] + bp[0];
    f32x4 s1 = hp[1] + dp[1] + bp[1];
    bf16x8 o;
#pragma unroll
    for (int j = 0; j < 4; ++j) {
        o[j]     = (__bf16)tanh_fast(s0[j]);
        o[4 + j] = (__bf16)tanh_fast(s1[j]);
    }
    *(bf16x8*)(h + rl * K_ + k8) = o;
}

// ---------------- joint GEMM: C[r,v] = h[r,:] . W2b[v,:] + b2[v] -----------
// 128x128 tile, BK=64, global_load_lds staging, XOR chunk swizzle.
__global__ __launch_bounds__(256) void joint_kernel(const __bf16* __restrict__ h,
                                                    const __bf16* __restrict__ W2b,
                                                    const float* __restrict__ b2,
                                                    float* __restrict__ out,
                                                    long r0) {
    const int ct = blockIdx.x;            // col tile 0..7 (V padded to 1024)
    const int rt = blockIdx.y;            // row tile within chunk

    __shared__ __align__(16) __bf16 As[128 * 64];
    __shared__ __align__(16) __bf16 Bs[128 * 64];

    const int tid  = threadIdx.x;
    const int lane = tid & 63, w = tid >> 6;
    const int wm = (w >> 1) * 64, wn = (w & 1) * 64;
    const int q = lane >> 4, li = lane & 15;

    // staging: lane l of wave w, issue i covers LDS row i*32 + w*8 + (l>>3),
    // LDS chunk (l&7); global k-chunk is XOR-swizzled.
    const int srow = lane >> 3;
    const int scol = ((lane & 7) ^ (srow & 7)) * 8;     // swizzled k offset
    const long aRow = (long)rt * 128 + w * 8 + srow;    // + i*32
    const long bRow = (long)ct * 128 + w * 8 + srow;    // + i*32
    const __bf16* aBase = h   + aRow * K_ + scol;
    const __bf16* bBase = W2b + bRow * K_ + scol;
    __bf16* aLds = As + w * 512;                        // + i*2048 (elems)
    __bf16* bLds = Bs + w * 512;

    // fragment read: row R = wm|wn + t*16 + li, byte addr R*128 + cswz
    const int cswz0 = ((q ^ (li & 7)) * 16);            // kk=0 chunk byte off
    const char* AsB = (const char*)As;
    const char* BsB = (const char*)Bs;

    f32x4 acc[4][4] = {};

    for (int k0 = 0; k0 < K_; k0 += 64) {
        __syncthreads();
#pragma unroll
        for (int i = 0; i < 4; ++i) {
            gl_lds16(aBase + (long)i * 32 * K_ + k0, aLds + i * 2048);
            gl_lds16(bBase + (long)i * 32 * K_ + k0, bLds + i * 2048);
        }
        __syncthreads();
#pragma unroll
        for (int kk = 0; kk < 2; ++kk) {
            const int cs = cswz0 ^ (kk << 6);
            bf16x8 af[4], bfr[4];
#pragma unroll
            for (int mi = 0; mi < 4; ++mi) af[mi]  = *(const bf16x8*)(AsB + (wm + mi * 16 + li) * 128 + cs);
#pragma unroll
            for (int ni = 0; ni < 4; ++ni) bfr[ni] = *(const bf16x8*)(BsB + (wn + ni * 16 + li) * 128 + cs);
#pragma unroll
            for (int mi = 0; mi < 4; ++mi)
#pragma unroll
                for (int ni = 0; ni < 4; ++ni)
                    acc[mi][ni] = __builtin_amdgcn_mfma_f32_16x16x32_bf16(af[mi], bfr[ni], acc[mi][ni], 0, 0, 0);
        }
    }

    const long rbase = r0 + (long)rt * 128 + wm;
#pragma unroll
    for (int ni = 0; ni < 4; ++ni) {
        int gv = ct * 128 + wn + ni * 16 + li;
        if (gv < V_) {
            float bb = b2[gv];
#pragma unroll
            for (int mi = 0; mi < 4; ++mi) {
                long rr = rbase + mi * 16 + q * 4;
                float* op = out + rr * V_ + gv;
                op[0L * V_] = acc[mi][ni][0] + bb;
                op[1L * V_] = acc[mi][ni][1] + bb;
                op[2L * V_] = acc[mi][ni][2] + bb;
                op[3L * V_] = acc[mi][ni][3] + bb;
            }
        }
    }
}

extern "C" void kernel_launch(void* const* d_in, const int* in_sizes, int n_in,
                              void* d_out, int out_size, void* d_ws, size_t ws_size,
                              hipStream_t stream) {
    const float* enc = (const float*)d_in[0];   // (4,256,512)
    const float* dec = (const float*)d_in[1];   // (4,64,512)
    const float* W1  = (const float*)d_in[2];   // (512,1024)
    const float* b1  = (const float*)d_in[3];   // (512,)
    const float* W2  = (const float*)d_in[4];   // (1000,512)
    const float* b2  = (const float*)d_in[5];   // (1000,)
    float* out = (float*)d_out;                 // (4,256,64,1000) fp32

    // workspace: he (2MB) | hd (0.5MB) | W2b (1MB, 1024 rows) | h (chunk)
    float*  he  = (float*)d_ws;
    float*  hd  = he + 1024 * K_;
    __bf16* W2b = (__bf16*)(hd + 256 * K_);
    __bf16* h   = W2b + 1024 * K_;
    const size_t fixed = (size_t)(1024 + 256) * K_ * 4 + (size_t)1024 * K_ * 2;

    long chunk = 0;
    if (ws_size > fixed) chunk = (long)((ws_size - fixed) / (K_ * 2)) & ~127L;
    if (chunk > ROWS_) chunk = ROWS_;
    if (chunk < 128) chunk = 128;               // assume ws is at least ~4MB

    w2conv_kernel<<<dim3(256), dim3(256), 0, stream>>>(W2, W2b);
    stage1_kernel<<<dim3(8, 20), dim3(256), 0, stream>>>(enc, dec, W1, he, hd);
    for (long r0 = 0; r0 < ROWS_; r0 += chunk) {
        long rows = ROWS_ - r0 < chunk ? ROWS_ - r0 : chunk;
        h_kernel<<<dim3((int)(rows / 4)), dim3(256), 0, stream>>>(he, hd, b1, h, r0);
        joint_kernel<<<dim3(8, (int)(rows / 128)), dim3(256), 0, stream>>>(h, W2b, b2, out, r0);
    }
}